// Round 4
// baseline (233.426 us; speedup 1.0000x reference)
//
#include <hip/hip_runtime.h>
#include <stdint.h>

#define ALPHA 0.2f
#define LOG2E 1.4426950408889634f

typedef __bf16 bf16x8 __attribute__((ext_vector_type(8)));
typedef float f32x4 __attribute__((ext_vector_type(4)));
typedef uint32_t u32x4 __attribute__((ext_vector_type(4)));

__device__ __forceinline__ uint32_t rotl32(uint32_t x, int r) {
  return __builtin_amdgcn_alignbit(x, x, 32 - r);
}

// JAX threefry2x32, key=(0,42), partitionable: counters (0,f), bits = x0^x1.
__device__ __forceinline__ uint32_t tf_mix(uint32_t f) {
  const uint32_t ks1 = 42u, ks2 = 0x1BD11BF0u;
  uint32_t x0 = 0u;
  uint32_t x1 = f + ks1;
#define TFR(r) { x0 += x1; x1 = rotl32(x1, r); x1 ^= x0; }
  TFR(13) TFR(15) TFR(26) TFR(6)  x0 += ks1; x1 += ks2 + 1u;
  TFR(17) TFR(29) TFR(16) TFR(24) x0 += ks2; x1 += 0u  + 2u;
  TFR(13) TFR(15) TFR(26) TFR(6)  x0 += 0u;  x1 += ks1 + 3u;
  TFR(17) TFR(29) TFR(16) TFR(24) x0 += ks1; x1 += ks2 + 4u;
  TFR(13) TFR(15) TFR(26) TFR(6)  x0 += ks2; x1 += 0u  + 5u;
#undef TFR
  return x0 ^ x1;
}

__device__ __forceinline__ unsigned short f2bf(float f) {  // RNE
  uint32_t u = __float_as_uint(f);
  return (unsigned short)((u + 0x7fffu + ((u >> 16) & 1u)) >> 16);
}

// K1: Wh = batch @ w (fp32 in LDS), bf16 Whb2 (MFMA-B-frag-friendly layout),
// fused s1/s2 + global max(s2) via atomicMax key.
// Whb2 idx(i,d) = (((i>>3)*16 + (d&15))*8 + (d>>4))*8 + (i&7)
__global__ __launch_bounds__(256) void wh_kernel(
    const float* __restrict__ batch, const float* __restrict__ w,
    const float* __restrict__ a, unsigned short* __restrict__ whb2,
    float* __restrict__ s1, float* __restrict__ s2, uint32_t* __restrict__ s2key) {
  __shared__ float whlds[32][128];  // 16 KB
  int t = threadIdx.x;
  int i0 = blockIdx.x * 32;
  int d = t & 127, rg = t >> 7;
  int ib = i0 + rg * 16;
  float acc[16];
#pragma unroll
  for (int r = 0; r < 16; ++r) acc[r] = 0.f;
  for (int k = 0; k < 128; k += 4) {
    float wv0 = w[(k + 0) * 128 + d];
    float wv1 = w[(k + 1) * 128 + d];
    float wv2 = w[(k + 2) * 128 + d];
    float wv3 = w[(k + 3) * 128 + d];
#pragma unroll
    for (int r = 0; r < 16; ++r) {
      float4 b4 = *(const float4*)&batch[(ib + r) * 128 + k];
      acc[r] = fmaf(b4.w, wv3, fmaf(b4.z, wv2, fmaf(b4.y, wv1, fmaf(b4.x, wv0, acc[r]))));
    }
  }
  unsigned short hb[16];
#pragma unroll
  for (int r = 0; r < 16; ++r) {
    whlds[rg * 16 + r][d] = acc[r];
    hb[r] = f2bf(acc[r]);
  }
  uint32_t pk[8];
#pragma unroll
  for (int q = 0; q < 8; ++q) pk[q] = (uint32_t)hb[2 * q] | ((uint32_t)hb[2 * q + 1] << 16);
  uint32_t base0 = (((uint32_t)(ib >> 3) * 16u + (uint32_t)(d & 15)) * 8u + (uint32_t)(d >> 4)) * 8u;
  *(uint4*)&whb2[base0]        = make_uint4(pk[0], pk[1], pk[2], pk[3]);  // i=ib..ib+7
  *(uint4*)&whb2[base0 + 1024] = make_uint4(pk[4], pk[5], pk[6], pk[7]); // i=ib+8..15
  __syncthreads();
  int rr = t >> 3, seg = t & 7, c0 = seg * 16;
  const float* wr = &whlds[rr][c0];
  float p1 = 0.f, p2 = 0.f;
#pragma unroll
  for (int c = 0; c < 16; ++c) {
    float v = wr[c];
    p1 = fmaf(v, a[c0 + c], p1);
    p2 = fmaf(v, a[128 + c0 + c], p2);
  }
  p1 += __shfl_xor(p1, 1, 64); p1 += __shfl_xor(p1, 2, 64); p1 += __shfl_xor(p1, 4, 64);
  p2 += __shfl_xor(p2, 1, 64); p2 += __shfl_xor(p2, 2, 64); p2 += __shfl_xor(p2, 4, 64);
  if (seg == 0) { s1[i0 + rr] = p1; s2[i0 + rr] = p2; }
  float v = (seg == 0) ? p2 : -3.4e38f;
#pragma unroll
  for (int m = 1; m <= 32; m <<= 1) v = fmaxf(v, __shfl_xor(v, m, 64));
  if ((t & 63) == 0) {
    uint32_t b = __float_as_uint(v);
    uint32_t key = (b & 0x80000000u) ? ~b : (b | 0x80000000u);
    atomicMax(s2key, key);
  }
}

// K2: barrier-free fused scores+softmax-num+dropout+PV.
// Block: 256 thr = 4 waves, 16 rows, j-chunk of 4096 (grid = 512 rb x 2 ck).
// Wave w, iter it: j-stripe = C0 + it*128 + w*32; lane (r=lane&15,q=lane>>4)
// computes 8 cols q*8+s -> exactly the MFMA A-fragment slots. P never hits LDS.
__global__ __launch_bounds__(256, 4) void gat_main(
    const float* __restrict__ s1, const float* __restrict__ s2g,
    const uint32_t* __restrict__ s2key, const unsigned short* __restrict__ whb2,
    float* __restrict__ pacc, float* __restrict__ pz) {
  __shared__ __align__(16) float smem[8256];  // [0,4096) sjL chunk; post-loop: red[4][2048] + zred[64]
  int t = threadIdx.x;
  int rb = blockIdx.x >> 1, ck = blockIdx.x & 1;
  int R0 = rb * 16, C0 = ck * 4096;

  for (int k = t; k < 1024; k += 256) {
    float4 v4 = ((const float4*)(s2g + C0))[k];
    v4.x *= LOG2E; v4.y *= LOG2E; v4.z *= LOG2E; v4.w *= LOG2E;
    ((float4*)smem)[k] = v4;
  }

  uint32_t kk = *s2key;
  uint32_t mb = (kk & 0x80000000u) ? (kk ^ 0x80000000u) : ~kk;
  float s2maxL = __uint_as_float(mb) * LOG2E;

  int w = t >> 6, lane = t & 63;
  int r = lane & 15, q = lane >> 4;

  // row constants (log2-domain, max folded): arg = max(u, fma(A,u,Cr)), u = Ar + sjL
  float s1L = s1[R0 + r] * LOG2E;
  float xmL = s1L + s2maxL;
  float mrL = fmaxf(xmL, ALPHA * xmL);
  float Ar = s1L - mrL;
  float Cr = (ALPHA - 1.f) * mrL;

  // threefry counter base: f = (R0+r)*8192 + C0 + w*32 + q*8 (+ it*128 + s)
  uint32_t fb = (uint32_t)(R0 + r) * 8192u + (uint32_t)(C0 + w * 32 + q * 8);
  // B voffset (bytes): (j8*16 + r)*128, j8 = C0/8 + w*4 + q; dt at imm offs 16*dt
  uint32_t voff = (((uint32_t)(C0 / 8 + w * 4 + q)) * 16u + (uint32_t)r) * 128u;
  const char* pB = (const char*)whb2;

  f32x4 acc[8];
#pragma unroll
  for (int dt = 0; dt < 8; ++dt) acc[dt] = (f32x4){0.f, 0.f, 0.f, 0.f};
  float z = 0.f;
  const uint32_t KTH = 0xE6666600u;  // keep <=> bits < 7549747<<9 (u < 0.9f)
  const float* sjb = smem + w * 32 + q * 8;

  __syncthreads();

  for (int it = 0; it < 32; ++it) {
    // 8 B-fragments: one voffset + imm offsets 0..112
    bf16x8 Bv[8];
#pragma unroll
    for (int dt = 0; dt < 8; ++dt)
      Bv[dt] = *(const bf16x8*)(pB + (voff + (uint32_t)(dt * 16)));
    float4 sj0 = *(const float4*)(sjb + it * 128);
    float4 sj1 = *(const float4*)(sjb + it * 128 + 4);
    uint32_t f0 = fb + (uint32_t)(it * 128);

    float p[8];
    {
      float sv[8] = {sj0.x, sj0.y, sj0.z, sj0.w, sj1.x, sj1.y, sj1.z, sj1.w};
#pragma unroll
      for (int s = 0; s < 8; ++s) {
        uint32_t bits = tf_mix(f0 + (uint32_t)s);
        float u = Ar + sv[s];
        float arg = fmaxf(u, fmaf(ALPHA, u, Cr));
        float pv = __builtin_amdgcn_exp2f(arg);
        z += pv;
        p[s] = (bits < KTH) ? pv : 0.f;
      }
    }
    bf16x8 A;
#pragma unroll
    for (int s = 0; s < 8; ++s) A[s] = (__bf16)p[s];

#pragma unroll
    for (int dt = 0; dt < 8; ++dt)
      acc[dt] = __builtin_amdgcn_mfma_f32_16x16x32_bf16(A, Bv[dt], acc[dt], 0, 0, 0);

    voff += 32768u;
  }

  // deterministic block reduction (4 wave partials) in LDS, then 2-addend atomics
  __syncthreads();  // sjL region dead; reuse as red
  float zq = z + __shfl_xor(z, 16, 64);
  zq += __shfl_xor(zq, 32, 64);
  if (lane < 16) smem[8192 + w * 16 + lane] = zq;
  float* red = smem;
#pragma unroll
  for (int dt = 0; dt < 8; ++dt) {
#pragma unroll
    for (int reg = 0; reg < 4; ++reg)
      red[w * 2048 + (4 * q + reg) * 128 + dt * 16 + r] = acc[dt][reg];
  }
  __syncthreads();
#pragma unroll
  for (int k2 = 0; k2 < 8; ++k2) {
    int idx = t * 8 + k2;
    float s = (red[idx] + red[2048 + idx]) + (red[4096 + idx] + red[6144 + idx]);
    atomicAdd(&pacc[(R0 + (idx >> 7)) * 128 + (idx & 127)], s);
  }
  if (t < 16) {
    float zs = (smem[8192 + t] + smem[8208 + t]) + (smem[8224 + t] + smem[8240 + t]);
    atomicAdd(&pz[R0 + t], zs);
  }
}

// K3: out = elu(pacc / (0.9 * pz))
__global__ __launch_bounds__(256) void gat_final(
    const float* __restrict__ pacc, const float* __restrict__ pz,
    float* __restrict__ out) {
  int t = threadIdx.x;
  int row = blockIdx.x * 8 + (t >> 5);
  int d4 = (t & 31) * 4;
  float zinv = 1.f / (0.9f * pz[row]);
  float4 p = *(const float4*)&pacc[row * 128 + d4];
  float4 o;
  float v;
  v = p.x * zinv; o.x = v > 0.f ? v : expm1f(v);
  v = p.y * zinv; o.y = v > 0.f ? v : expm1f(v);
  v = p.z * zinv; o.z = v > 0.f ? v : expm1f(v);
  v = p.w * zinv; o.w = v > 0.f ? v : expm1f(v);
  *(float4*)&out[row * 128 + d4] = o;
}

extern "C" void kernel_launch(void* const* d_in, const int* in_sizes, int n_in,
                              void* d_out, int out_size, void* d_ws, size_t ws_size,
                              hipStream_t stream) {
  const float* batch = (const float*)d_in[0];
  const float* w = (const float*)d_in[1];
  const float* a = (const float*)d_in[2];
  float* out = (float*)d_out;
  char* ws = (char*)d_ws;
  // layout: [pacc 4MB][pz 32KB][s2key 64B][whb2 2MB][s1 32KB][s2 32KB]
  float* pacc = (float*)ws;
  float* pz = (float*)(ws + 4194304);
  uint32_t* s2key = (uint32_t*)(ws + 4194304 + 32768);
  unsigned short* whb2 = (unsigned short*)(ws + 4194304 + 32768 + 64);
  float* s1 = (float*)(ws + 4194304 + 32768 + 64 + 2097152);
  float* s2 = (float*)(ws + 4194304 + 32768 + 64 + 2097152 + 32768);

  hipMemsetAsync(ws, 0, 4194304 + 32768 + 64, stream);  // pacc + pz + s2key
  wh_kernel<<<256, 256, 0, stream>>>(batch, w, a, whb2, s1, s2, s2key);
  gat_main<<<1024, 256, 0, stream>>>(s1, s2, s2key, whb2, pacc, pz);
  gat_final<<<1024, 256, 0, stream>>>(pacc, pz, out);
}

// Round 5
// 196.162 us; speedup vs baseline: 1.1900x; 1.1900x over previous
//
#include <hip/hip_runtime.h>
#include <stdint.h>

#define ALPHA 0.2f
#define LOG2E 1.4426950408889634f

typedef __bf16 bf16x8 __attribute__((ext_vector_type(8)));
typedef float f32x4 __attribute__((ext_vector_type(4)));

__device__ __forceinline__ uint32_t rotl32(uint32_t x, int r) {
  return __builtin_amdgcn_alignbit(x, x, 32 - r);
}

// JAX threefry2x32, key=(0,42), partitionable: counters (0,f), bits = x0^x1.
__device__ __forceinline__ uint32_t tf_mix(uint32_t f) {
  const uint32_t ks1 = 42u, ks2 = 0x1BD11BF0u;
  uint32_t x0 = 0u;
  uint32_t x1 = f + ks1;
#define TFR(r) { x0 += x1; x1 = rotl32(x1, r); x1 ^= x0; }
  TFR(13) TFR(15) TFR(26) TFR(6)  x0 += ks1; x1 += ks2 + 1u;
  TFR(17) TFR(29) TFR(16) TFR(24) x0 += ks2; x1 += 0u  + 2u;
  TFR(13) TFR(15) TFR(26) TFR(6)  x0 += 0u;  x1 += ks1 + 3u;
  TFR(17) TFR(29) TFR(16) TFR(24) x0 += ks1; x1 += ks2 + 4u;
  TFR(13) TFR(15) TFR(26) TFR(6)  x0 += ks2; x1 += 0u  + 5u;
#undef TFR
  return x0 ^ x1;
}

__device__ __forceinline__ unsigned short f2bf(float f) {  // RNE
  uint32_t u = __float_as_uint(f);
  return (unsigned short)((u + 0x7fffu + ((u >> 16) & 1u)) >> 16);
}

// K1: Wh = batch @ w (fp32 in LDS), bf16 whb2 (MFMA-B-frag layout),
// fused s1/s2 + global max(s2) via atomicMax key.
// whb2 idx(i,d) = (((i>>3)*16 + (d&15))*8 + (d>>4))*8 + (i&7)
__global__ __launch_bounds__(256) void wh_kernel(
    const float* __restrict__ batch, const float* __restrict__ w,
    const float* __restrict__ a, unsigned short* __restrict__ whb2,
    float* __restrict__ s1, float* __restrict__ s2, uint32_t* __restrict__ s2key) {
  __shared__ float whlds[32][128];  // 16 KB
  int t = threadIdx.x;
  int i0 = blockIdx.x * 32;
  int d = t & 127, rg = t >> 7;
  int ib = i0 + rg * 16;
  float acc[16];
#pragma unroll
  for (int r = 0; r < 16; ++r) acc[r] = 0.f;
  for (int k = 0; k < 128; k += 4) {
    float wv0 = w[(k + 0) * 128 + d];
    float wv1 = w[(k + 1) * 128 + d];
    float wv2 = w[(k + 2) * 128 + d];
    float wv3 = w[(k + 3) * 128 + d];
#pragma unroll
    for (int r = 0; r < 16; ++r) {
      float4 b4 = *(const float4*)&batch[(ib + r) * 128 + k];
      acc[r] = fmaf(b4.w, wv3, fmaf(b4.z, wv2, fmaf(b4.y, wv1, fmaf(b4.x, wv0, acc[r]))));
    }
  }
  unsigned short hb[16];
#pragma unroll
  for (int r = 0; r < 16; ++r) {
    whlds[rg * 16 + r][d] = acc[r];
    hb[r] = f2bf(acc[r]);
  }
  uint32_t pk[8];
#pragma unroll
  for (int q = 0; q < 8; ++q) pk[q] = (uint32_t)hb[2 * q] | ((uint32_t)hb[2 * q + 1] << 16);
  uint32_t base0 = (((uint32_t)(ib >> 3) * 16u + (uint32_t)(d & 15)) * 8u + (uint32_t)(d >> 4)) * 8u;
  *(uint4*)&whb2[base0]        = make_uint4(pk[0], pk[1], pk[2], pk[3]);
  *(uint4*)&whb2[base0 + 1024] = make_uint4(pk[4], pk[5], pk[6], pk[7]);
  __syncthreads();
  int rr = t >> 3, seg = t & 7, c0 = seg * 16;
  const float* wr = &whlds[rr][c0];
  float p1 = 0.f, p2 = 0.f;
#pragma unroll
  for (int c = 0; c < 16; ++c) {
    float v = wr[c];
    p1 = fmaf(v, a[c0 + c], p1);
    p2 = fmaf(v, a[128 + c0 + c], p2);
  }
  p1 += __shfl_xor(p1, 1, 64); p1 += __shfl_xor(p1, 2, 64); p1 += __shfl_xor(p1, 4, 64);
  p2 += __shfl_xor(p2, 1, 64); p2 += __shfl_xor(p2, 2, 64); p2 += __shfl_xor(p2, 4, 64);
  if (seg == 0) { s1[i0 + rr] = p1; s2[i0 + rr] = p2; }
  float v = (seg == 0) ? p2 : -3.4e38f;
#pragma unroll
  for (int m = 1; m <= 32; m <<= 1) v = fmaxf(v, __shfl_xor(v, m, 64));
  if ((t & 63) == 0) {
    uint32_t b = __float_as_uint(v);
    uint32_t key = (b & 0x80000000u) ? ~b : (b | 0x80000000u);
    atomicMax(s2key, key);
  }
}

// K2: barrier-free fused scores+softmax-num+dropout+PV.
// p[i,j] = exp2(max(u,αu) - m) = max(F1_i*E1_j, F2_i*E2_j)  (exp2 monotone),
// E1/E2 tabulated in LDS, F1/F2 per row. No transcendental in hot loop.
__global__ __launch_bounds__(256) __attribute__((amdgpu_waves_per_eu(4, 4)))
void gat_main(
    const float* __restrict__ s1, const float* __restrict__ s2g,
    const uint32_t* __restrict__ s2key, const unsigned short* __restrict__ whb2,
    float* __restrict__ pacc, float* __restrict__ pz) {
  __shared__ __align__(16) float smem[8256];  // E-pairs [0,8192); epilogue: red + zred[8192,8256)
  int t = threadIdx.x;
  int rb = blockIdx.x >> 1, ck = blockIdx.x & 1;
  int R0 = rb * 16, C0 = ck * 4096;

  // Build E table: smem as float2[4096] = (E1_j, E2_j) for chunk cols.
  for (int k = t; k < 4096; k += 256) {
    float sL = s2g[C0 + k] * LOG2E;
    float e1 = __builtin_amdgcn_exp2f(sL);
    float e2 = __builtin_amdgcn_exp2f(ALPHA * sL);
    ((float2*)smem)[k] = make_float2(e1, e2);
  }

  uint32_t kk = *s2key;
  uint32_t mb = (kk & 0x80000000u) ? (kk ^ 0x80000000u) : ~kk;
  float s2maxL = __uint_as_float(mb) * LOG2E;

  int w = t >> 6, lane = t & 63;
  int r = lane & 15, q = lane >> 4;

  float s1L = s1[R0 + r] * LOG2E;
  float xmL = s1L + s2maxL;
  float mrL = fmaxf(xmL, ALPHA * xmL);   // exact row max (log2 domain)
  float F1 = __builtin_amdgcn_exp2f(s1L - mrL);
  float F2 = __builtin_amdgcn_exp2f(fmaf(ALPHA, s1L, -mrL));

  uint32_t fcur = (uint32_t)(R0 + r) * 8192u + (uint32_t)(C0 + w * 32 + q * 8);
  uint32_t voff = (((uint32_t)(C0 / 8 + w * 4 + q)) * 16u + (uint32_t)r) * 128u;
  const char* pB = (const char*)whb2;
  const float2* Eb = ((const float2*)smem) + w * 32 + q * 8;

  f32x4 acc0 = {0,0,0,0}, acc1 = {0,0,0,0}, acc2 = {0,0,0,0}, acc3 = {0,0,0,0};
  f32x4 acc4 = {0,0,0,0}, acc5 = {0,0,0,0}, acc6 = {0,0,0,0}, acc7 = {0,0,0,0};
  float z = 0.f;
  const uint32_t KTH = 0xE6666600u;  // keep <=> bits < 7549747<<9 (u < 0.9f)

  __syncthreads();

  for (int it = 0; it < 32; ++it) {
    bf16x8 B0 = *(const bf16x8*)(pB + voff);
    bf16x8 B1 = *(const bf16x8*)(pB + voff + 16);
    bf16x8 B2 = *(const bf16x8*)(pB + voff + 32);
    bf16x8 B3 = *(const bf16x8*)(pB + voff + 48);
    bf16x8 B4 = *(const bf16x8*)(pB + voff + 64);
    bf16x8 B5 = *(const bf16x8*)(pB + voff + 80);
    bf16x8 B6 = *(const bf16x8*)(pB + voff + 96);
    bf16x8 B7 = *(const bf16x8*)(pB + voff + 112);
    float4 E01 = *(const float4*)(Eb);      // (E1,E2) for elems 0,1
    float4 E23 = *(const float4*)(Eb + 2);
    float4 E45 = *(const float4*)(Eb + 4);
    float4 E67 = *(const float4*)(Eb + 6);
    __builtin_amdgcn_sched_barrier(0);

    bf16x8 A;
#define ELEM(idx, e1v, e2v)                                   \
    {                                                         \
      uint32_t bb = tf_mix(fcur + idx);                       \
      float pv = fmaxf(F1 * (e1v), F2 * (e2v));               \
      z += pv;                                                \
      pv = (bb < KTH) ? pv : 0.f;                             \
      A[idx] = (__bf16)pv;                                    \
    }
    ELEM(0, E01.x, E01.y)
    ELEM(1, E01.z, E01.w)
    ELEM(2, E23.x, E23.y)
    ELEM(3, E23.z, E23.w)
    ELEM(4, E45.x, E45.y)
    ELEM(5, E45.z, E45.w)
    ELEM(6, E67.x, E67.y)
    ELEM(7, E67.z, E67.w)
#undef ELEM

    acc0 = __builtin_amdgcn_mfma_f32_16x16x32_bf16(A, B0, acc0, 0, 0, 0);
    acc1 = __builtin_amdgcn_mfma_f32_16x16x32_bf16(A, B1, acc1, 0, 0, 0);
    acc2 = __builtin_amdgcn_mfma_f32_16x16x32_bf16(A, B2, acc2, 0, 0, 0);
    acc3 = __builtin_amdgcn_mfma_f32_16x16x32_bf16(A, B3, acc3, 0, 0, 0);
    acc4 = __builtin_amdgcn_mfma_f32_16x16x32_bf16(A, B4, acc4, 0, 0, 0);
    acc5 = __builtin_amdgcn_mfma_f32_16x16x32_bf16(A, B5, acc5, 0, 0, 0);
    acc6 = __builtin_amdgcn_mfma_f32_16x16x32_bf16(A, B6, acc6, 0, 0, 0);
    acc7 = __builtin_amdgcn_mfma_f32_16x16x32_bf16(A, B7, acc7, 0, 0, 0);

    fcur += 128u;
    voff += 32768u;
    Eb += 128;
  }

  // deterministic epilogue: LDS tree over 4 wave-partials, 2-addend atomics
  __syncthreads();
  float zq = z + __shfl_xor(z, 16, 64);
  zq += __shfl_xor(zq, 32, 64);
  if (lane < 16) smem[8192 + w * 16 + lane] = zq;
  float* red = smem;
#define STORE(dt, accN)                                                  \
  {                                                                      \
    red[w * 2048 + (4 * q + 0) * 128 + dt * 16 + r] = accN[0];           \
    red[w * 2048 + (4 * q + 1) * 128 + dt * 16 + r] = accN[1];           \
    red[w * 2048 + (4 * q + 2) * 128 + dt * 16 + r] = accN[2];           \
    red[w * 2048 + (4 * q + 3) * 128 + dt * 16 + r] = accN[3];           \
  }
  STORE(0, acc0) STORE(1, acc1) STORE(2, acc2) STORE(3, acc3)
  STORE(4, acc4) STORE(5, acc5) STORE(6, acc6) STORE(7, acc7)
#undef STORE
  __syncthreads();
#pragma unroll
  for (int k2 = 0; k2 < 8; ++k2) {
    int idx = t * 8 + k2;
    float s = (red[idx] + red[2048 + idx]) + (red[4096 + idx] + red[6144 + idx]);
    atomicAdd(&pacc[(R0 + (idx >> 7)) * 128 + (idx & 127)], s);
  }
  if (t < 16) {
    float zs = (smem[8192 + t] + smem[8208 + t]) + (smem[8224 + t] + smem[8240 + t]);
    atomicAdd(&pz[R0 + t], zs);
  }
}

// K3: out = elu(pacc / (0.9 * pz))
__global__ __launch_bounds__(256) void gat_final(
    const float* __restrict__ pacc, const float* __restrict__ pz,
    float* __restrict__ out) {
  int t = threadIdx.x;
  int row = blockIdx.x * 8 + (t >> 5);
  int d4 = (t & 31) * 4;
  float zinv = 1.f / (0.9f * pz[row]);
  float4 p = *(const float4*)&pacc[row * 128 + d4];
  float4 o;
  float v;
  v = p.x * zinv; o.x = v > 0.f ? v : expm1f(v);
  v = p.y * zinv; o.y = v > 0.f ? v : expm1f(v);
  v = p.z * zinv; o.z = v > 0.f ? v : expm1f(v);
  v = p.w * zinv; o.w = v > 0.f ? v : expm1f(v);
  *(float4*)&out[row * 128 + d4] = o;
}

extern "C" void kernel_launch(void* const* d_in, const int* in_sizes, int n_in,
                              void* d_out, int out_size, void* d_ws, size_t ws_size,
                              hipStream_t stream) {
  const float* batch = (const float*)d_in[0];
  const float* w = (const float*)d_in[1];
  const float* a = (const float*)d_in[2];
  float* out = (float*)d_out;
  char* ws = (char*)d_ws;
  // layout: [pacc 4MB][pz 32KB][s2key 64B][whb2 2MB][s1 32KB][s2 32KB]
  float* pacc = (float*)ws;
  float* pz = (float*)(ws + 4194304);
  uint32_t* s2key = (uint32_t*)(ws + 4194304 + 32768);
  unsigned short* whb2 = (unsigned short*)(ws + 4194304 + 32768 + 64);
  float* s1 = (float*)(ws + 4194304 + 32768 + 64 + 2097152);
  float* s2 = (float*)(ws + 4194304 + 32768 + 64 + 2097152 + 32768);

  hipMemsetAsync(ws, 0, 4194304 + 32768 + 64, stream);  // pacc + pz + s2key
  wh_kernel<<<256, 256, 0, stream>>>(batch, w, a, whb2, s1, s2, s2key);
  gat_main<<<1024, 256, 0, stream>>>(s1, s2, s2key, whb2, pacc, pz);
  gat_final<<<1024, 256, 0, stream>>>(pacc, pz, out);
}

// Round 6
// 175.625 us; speedup vs baseline: 1.3291x; 1.1169x over previous
//
#include <hip/hip_runtime.h>
#include <stdint.h>

#define ALPHA 0.2f
#define LOG2E 1.4426950408889634f

typedef __bf16 bf16x8 __attribute__((ext_vector_type(8)));
typedef float f32x4 __attribute__((ext_vector_type(4)));

__device__ __forceinline__ uint32_t rotl32(uint32_t x, int r) {
  return __builtin_amdgcn_alignbit(x, x, 32 - r);
}

// JAX threefry2x32, key=(0,42), partitionable: counters (0,f), bits = x0^x1.
__device__ __forceinline__ uint32_t tf_mix(uint32_t f) {
  const uint32_t ks1 = 42u, ks2 = 0x1BD11BF0u;
  uint32_t x0 = 0u;
  uint32_t x1 = f + ks1;
#define TFR(r) { x0 += x1; x1 = rotl32(x1, r); x1 ^= x0; }
  TFR(13) TFR(15) TFR(26) TFR(6)  x0 += ks1; x1 += ks2 + 1u;
  TFR(17) TFR(29) TFR(16) TFR(24) x0 += ks2; x1 += 0u  + 2u;
  TFR(13) TFR(15) TFR(26) TFR(6)  x0 += 0u;  x1 += ks1 + 3u;
  TFR(17) TFR(29) TFR(16) TFR(24) x0 += ks1; x1 += ks2 + 4u;
  TFR(13) TFR(15) TFR(26) TFR(6)  x0 += ks2; x1 += 0u  + 5u;
#undef TFR
  return x0 ^ x1;
}

__device__ __forceinline__ unsigned short f2bf(float f) {  // RNE
  uint32_t u = __float_as_uint(f);
  return (unsigned short)((u + 0x7fffu + ((u >> 16) & 1u)) >> 16);
}

// K1: Wh = batch @ w (fp32 in LDS), bf16 whb2 (MFMA-B-frag layout),
// fused s1/s2 + global max(s2) via atomicMax key.
// whb2 idx(i,d) = (((i>>3)*16 + (d&15))*8 + (d>>4))*8 + (i&7)
__global__ __launch_bounds__(256) void wh_kernel(
    const float* __restrict__ batch, const float* __restrict__ w,
    const float* __restrict__ a, unsigned short* __restrict__ whb2,
    float* __restrict__ s1, float* __restrict__ s2, uint32_t* __restrict__ s2key) {
  __shared__ float whlds[32][128];  // 16 KB
  int t = threadIdx.x;
  int i0 = blockIdx.x * 32;
  int d = t & 127, rg = t >> 7;
  int ib = i0 + rg * 16;
  float acc[16];
#pragma unroll
  for (int r = 0; r < 16; ++r) acc[r] = 0.f;
  for (int k = 0; k < 128; k += 4) {
    float wv0 = w[(k + 0) * 128 + d];
    float wv1 = w[(k + 1) * 128 + d];
    float wv2 = w[(k + 2) * 128 + d];
    float wv3 = w[(k + 3) * 128 + d];
#pragma unroll
    for (int r = 0; r < 16; ++r) {
      float4 b4 = *(const float4*)&batch[(ib + r) * 128 + k];
      acc[r] = fmaf(b4.w, wv3, fmaf(b4.z, wv2, fmaf(b4.y, wv1, fmaf(b4.x, wv0, acc[r]))));
    }
  }
  unsigned short hb[16];
#pragma unroll
  for (int r = 0; r < 16; ++r) {
    whlds[rg * 16 + r][d] = acc[r];
    hb[r] = f2bf(acc[r]);
  }
  uint32_t pk[8];
#pragma unroll
  for (int q = 0; q < 8; ++q) pk[q] = (uint32_t)hb[2 * q] | ((uint32_t)hb[2 * q + 1] << 16);
  uint32_t base0 = (((uint32_t)(ib >> 3) * 16u + (uint32_t)(d & 15)) * 8u + (uint32_t)(d >> 4)) * 8u;
  *(uint4*)&whb2[base0]        = make_uint4(pk[0], pk[1], pk[2], pk[3]);
  *(uint4*)&whb2[base0 + 1024] = make_uint4(pk[4], pk[5], pk[6], pk[7]);
  __syncthreads();
  int rr = t >> 3, seg = t & 7, c0 = seg * 16;
  const float* wr = &whlds[rr][c0];
  float p1 = 0.f, p2 = 0.f;
#pragma unroll
  for (int c = 0; c < 16; ++c) {
    float v = wr[c];
    p1 = fmaf(v, a[c0 + c], p1);
    p2 = fmaf(v, a[128 + c0 + c], p2);
  }
  p1 += __shfl_xor(p1, 1, 64); p1 += __shfl_xor(p1, 2, 64); p1 += __shfl_xor(p1, 4, 64);
  p2 += __shfl_xor(p2, 1, 64); p2 += __shfl_xor(p2, 2, 64); p2 += __shfl_xor(p2, 4, 64);
  if (seg == 0) { s1[i0 + rr] = p1; s2[i0 + rr] = p2; }
  float v = (seg == 0) ? p2 : -3.4e38f;
#pragma unroll
  for (int m = 1; m <= 32; m <<= 1) v = fmaxf(v, __shfl_xor(v, m, 64));
  if ((t & 63) == 0) {
    uint32_t b = __float_as_uint(v);
    uint32_t key = (b & 0x80000000u) ? ~b : (b | 0x80000000u);
    atomicMax(s2key, key);
  }
}

// K2: barrier-free fused scores+softmax-num+dropout+PV.
// p[i,j] = exp2(max(u,au) - m) = max(F1_i*E1_j, F2_i*E2_j); E tabulated in LDS.
// Grid: 512 rb x 4 ck = 2048 blocks (8/CU), chunk = 2048 cols, 16 iters.
__global__ __launch_bounds__(256, 4) void gat_main(
    const float* __restrict__ s1, const float* __restrict__ s2g,
    const uint32_t* __restrict__ s2key, const unsigned short* __restrict__ whb2,
    float* __restrict__ pacc, float* __restrict__ pz) {
  __shared__ __align__(16) float smem[4160];  // E [0,4096); zred [4096,4160); red reuses [0,4096)
  int t = threadIdx.x;
  int rb = blockIdx.x >> 2, ck = blockIdx.x & 3;
  int R0 = rb * 16, C0 = ck * 2048;

  // Build E table: (E1_j, E2_j) float2 per chunk col.
  for (int k = t; k < 512; k += 256) {
    float4 v4 = ((const float4*)(s2g + C0))[k];
    float sL, e1, e2;
    sL = v4.x * LOG2E; e1 = __builtin_amdgcn_exp2f(sL); e2 = __builtin_amdgcn_exp2f(ALPHA * sL);
    ((float2*)smem)[k * 4 + 0] = make_float2(e1, e2);
    sL = v4.y * LOG2E; e1 = __builtin_amdgcn_exp2f(sL); e2 = __builtin_amdgcn_exp2f(ALPHA * sL);
    ((float2*)smem)[k * 4 + 1] = make_float2(e1, e2);
    sL = v4.z * LOG2E; e1 = __builtin_amdgcn_exp2f(sL); e2 = __builtin_amdgcn_exp2f(ALPHA * sL);
    ((float2*)smem)[k * 4 + 2] = make_float2(e1, e2);
    sL = v4.w * LOG2E; e1 = __builtin_amdgcn_exp2f(sL); e2 = __builtin_amdgcn_exp2f(ALPHA * sL);
    ((float2*)smem)[k * 4 + 3] = make_float2(e1, e2);
  }

  uint32_t kk = *s2key;
  uint32_t mb = (kk & 0x80000000u) ? (kk ^ 0x80000000u) : ~kk;
  float s2maxL = __uint_as_float(mb) * LOG2E;

  int w = t >> 6, lane = t & 63;
  int r = lane & 15, q = lane >> 4;

  float s1L = s1[R0 + r] * LOG2E;
  float xmL = s1L + s2maxL;
  float mrL = fmaxf(xmL, ALPHA * xmL);   // exact row max (log2 domain)
  float F1 = __builtin_amdgcn_exp2f(s1L - mrL);
  float F2 = __builtin_amdgcn_exp2f(fmaf(ALPHA, s1L, -mrL));

  uint32_t fcur = (uint32_t)(R0 + r) * 8192u + (uint32_t)(C0 + w * 32 + q * 8);
  uint32_t voff = (((uint32_t)(C0 / 8 + w * 4 + q)) * 16u + (uint32_t)r) * 128u;
  const char* pB = (const char*)whb2;
  const float2* Eb = ((const float2*)smem) + w * 32 + q * 8;

  f32x4 acc0 = {0,0,0,0}, acc1 = {0,0,0,0}, acc2 = {0,0,0,0}, acc3 = {0,0,0,0};
  f32x4 acc4 = {0,0,0,0}, acc5 = {0,0,0,0}, acc6 = {0,0,0,0}, acc7 = {0,0,0,0};
  float z = 0.f;
  const uint32_t KTH = 0xE6666600u;  // keep <=> bits < 7549747<<9 (u < 0.9f)

  __syncthreads();

  for (int it = 0; it < 16; ++it) {
    bf16x8 B0 = *(const bf16x8*)(pB + voff);
    bf16x8 B1 = *(const bf16x8*)(pB + voff + 16);
    bf16x8 B2 = *(const bf16x8*)(pB + voff + 32);
    bf16x8 B3 = *(const bf16x8*)(pB + voff + 48);
    bf16x8 B4 = *(const bf16x8*)(pB + voff + 64);
    bf16x8 B5 = *(const bf16x8*)(pB + voff + 80);
    bf16x8 B6 = *(const bf16x8*)(pB + voff + 96);
    bf16x8 B7 = *(const bf16x8*)(pB + voff + 112);
    float4 E01 = *(const float4*)(Eb);
    float4 E23 = *(const float4*)(Eb + 2);
    float4 E45 = *(const float4*)(Eb + 4);
    float4 E67 = *(const float4*)(Eb + 6);
    __builtin_amdgcn_sched_barrier(0);

    bf16x8 A;
#define ELEM(idx, e1v, e2v)                                   \
    {                                                         \
      uint32_t bb = tf_mix(fcur + idx);                       \
      float pv = fmaxf(F1 * (e1v), F2 * (e2v));               \
      z += pv;                                                \
      pv = (bb < KTH) ? pv : 0.f;                             \
      A[idx] = (__bf16)pv;                                    \
    }
    ELEM(0, E01.x, E01.y)
    ELEM(1, E01.z, E01.w)
    ELEM(2, E23.x, E23.y)
    ELEM(3, E23.z, E23.w)
    ELEM(4, E45.x, E45.y)
    ELEM(5, E45.z, E45.w)
    ELEM(6, E67.x, E67.y)
    ELEM(7, E67.z, E67.w)
#undef ELEM

    acc0 = __builtin_amdgcn_mfma_f32_16x16x32_bf16(A, B0, acc0, 0, 0, 0);
    acc1 = __builtin_amdgcn_mfma_f32_16x16x32_bf16(A, B1, acc1, 0, 0, 0);
    acc2 = __builtin_amdgcn_mfma_f32_16x16x32_bf16(A, B2, acc2, 0, 0, 0);
    acc3 = __builtin_amdgcn_mfma_f32_16x16x32_bf16(A, B3, acc3, 0, 0, 0);
    acc4 = __builtin_amdgcn_mfma_f32_16x16x32_bf16(A, B4, acc4, 0, 0, 0);
    acc5 = __builtin_amdgcn_mfma_f32_16x16x32_bf16(A, B5, acc5, 0, 0, 0);
    acc6 = __builtin_amdgcn_mfma_f32_16x16x32_bf16(A, B6, acc6, 0, 0, 0);
    acc7 = __builtin_amdgcn_mfma_f32_16x16x32_bf16(A, B7, acc7, 0, 0, 0);

    fcur += 128u;
    voff += 32768u;
    Eb += 128;
  }

  // epilogue: z reduce + two 8KB LDS reduction rounds over the 4 wave-partials
  __syncthreads();  // all waves done reading E
  float zq = z + __shfl_xor(z, 16, 64);
  zq += __shfl_xor(zq, 32, 64);
  if (lane < 16) smem[4096 + w * 16 + lane] = zq;

  float* red = smem;
  int wbase = w * 1024 + q * 256 + r;
#define STOREG(u, accN)                                \
  {                                                    \
    red[wbase + 0 * 64 + (u) * 16] = accN[0];          \
    red[wbase + 1 * 64 + (u) * 16] = accN[1];          \
    red[wbase + 2 * 64 + (u) * 16] = accN[2];          \
    red[wbase + 3 * 64 + (u) * 16] = accN[3];          \
  }
  // group 0: dt 0..3 -> out cols 0..63
  STOREG(0, acc0) STOREG(1, acc1) STOREG(2, acc2) STOREG(3, acc3)
  __syncthreads();
#pragma unroll
  for (int k2 = 0; k2 < 4; ++k2) {
    int idx = t * 4 + k2;
    float s = (red[idx] + red[1024 + idx]) + (red[2048 + idx] + red[3072 + idx]);
    atomicAdd(&pacc[(R0 + (idx >> 6)) * 128 + (idx & 63)], s);
  }
  __syncthreads();
  // group 1: dt 4..7 -> out cols 64..127
  STOREG(0, acc4) STOREG(1, acc5) STOREG(2, acc6) STOREG(3, acc7)
#undef STOREG
  __syncthreads();
#pragma unroll
  for (int k2 = 0; k2 < 4; ++k2) {
    int idx = t * 4 + k2;
    float s = (red[idx] + red[1024 + idx]) + (red[2048 + idx] + red[3072 + idx]);
    atomicAdd(&pacc[(R0 + (idx >> 6)) * 128 + 64 + (idx & 63)], s);
  }
  if (t < 16) {
    float zs = (smem[4096 + t] + smem[4112 + t]) + (smem[4128 + t] + smem[4144 + t]);
    atomicAdd(&pz[R0 + t], zs);
  }
}

// K3: out = elu(pacc / (0.9 * pz))
__global__ __launch_bounds__(256) void gat_final(
    const float* __restrict__ pacc, const float* __restrict__ pz,
    float* __restrict__ out) {
  int t = threadIdx.x;
  int row = blockIdx.x * 8 + (t >> 5);
  int d4 = (t & 31) * 4;
  float zinv = 1.f / (0.9f * pz[row]);
  float4 p = *(const float4*)&pacc[row * 128 + d4];
  float4 o;
  float v;
  v = p.x * zinv; o.x = v > 0.f ? v : expm1f(v);
  v = p.y * zinv; o.y = v > 0.f ? v : expm1f(v);
  v = p.z * zinv; o.z = v > 0.f ? v : expm1f(v);
  v = p.w * zinv; o.w = v > 0.f ? v : expm1f(v);
  *(float4*)&out[row * 128 + d4] = o;
}

extern "C" void kernel_launch(void* const* d_in, const int* in_sizes, int n_in,
                              void* d_out, int out_size, void* d_ws, size_t ws_size,
                              hipStream_t stream) {
  const float* batch = (const float*)d_in[0];
  const float* w = (const float*)d_in[1];
  const float* a = (const float*)d_in[2];
  float* out = (float*)d_out;
  char* ws = (char*)d_ws;
  // layout: [pacc 4MB][pz 32KB][s2key 64B][whb2 2MB][s1 32KB][s2 32KB]
  float* pacc = (float*)ws;
  float* pz = (float*)(ws + 4194304);
  uint32_t* s2key = (uint32_t*)(ws + 4194304 + 32768);
  unsigned short* whb2 = (unsigned short*)(ws + 4194304 + 32768 + 64);
  float* s1 = (float*)(ws + 4194304 + 32768 + 64 + 2097152);
  float* s2 = (float*)(ws + 4194304 + 32768 + 64 + 2097152 + 32768);

  hipMemsetAsync(ws, 0, 4194304 + 32768 + 64, stream);  // pacc + pz + s2key
  wh_kernel<<<256, 256, 0, stream>>>(batch, w, a, whb2, s1, s2, s2key);
  gat_main<<<2048, 256, 0, stream>>>(s1, s2, s2key, whb2, pacc, pz);
  gat_final<<<1024, 256, 0, stream>>>(pacc, pz, out);
}